// Round 3
// baseline (282.829 us; speedup 1.0000x reference)
//
#include <hip/hip_runtime.h>
#include <math.h>

// Problem constants (fixed by setup_inputs: B=64, C=1, H=512, W=512 fp32)
static constexpr int Hdim = 512;
static constexpr int Wdim = 512;
static constexpr int HW   = Hdim * Wdim;       // 2^18 px per image
static constexpr int RSTRIP = 16;              // rows per block strip
static constexpr int SPI  = Hdim / RSTRIP;     // strips per image = 32
static constexpr int NBLK = 64 * SPI;          // 2048 blocks = 8/CU resident
static constexpr int WPR  = Wdim / 64;         // 8 uint64 words per row
static constexpr int MROWS = RSTRIP + 4;       // mask rows incl. +/-2 halo

// d_ws: [0..4] double accumulators (focal, inter, sum_p, sum_t, bce*w), [5] ticket
__global__ void zero_ws_kernel(double* ws) {
    if (threadIdx.x < 6) ws[threadIdx.x] = 0.0;
}

__device__ __forceinline__ unsigned long long shl1(unsigned long long c, unsigned long long l) {
    return (c << 1) | (l >> 63);   // value at x-1
}
__device__ __forceinline__ unsigned long long shr1(unsigned long long c, unsigned long long r) {
    return (c >> 1) | (r << 63);   // value at x+1
}
__device__ __forceinline__ unsigned long long shl2(unsigned long long c, unsigned long long l) {
    return (c << 2) | (l >> 62);
}
__device__ __forceinline__ unsigned long long shr2(unsigned long long c, unsigned long long r) {
    return (c >> 2) | (r << 62);
}

__global__ __launch_bounds__(256, 8) void combined_loss_kernel(
    const float* __restrict__ inp, const float* __restrict__ tgt,
    double* __restrict__ acc, float* __restrict__ out)
{
    __shared__ unsigned long long tmask[MROWS][WPR];   // rows r0-2 .. r0+RSTRIP+1
    __shared__ unsigned long long bmask[RSTRIP][WPR];  // boundary bits
    __shared__ float smem[4][5];

    const int img   = blockIdx.x / SPI;
    const int strip = blockIdx.x % SPI;
    const int r0    = strip * RSTRIP;
    const float* tb = tgt + img * HW;
    const float* ib = inp + img * HW;

    const int wave = threadIdx.x >> 6;
    const int lane = threadIdx.x & 63;

    // ---- Phase 1: build target bitmask. Each thread: 16 px -> one ushort chunk ----
    // chunk c (0..MROWS*32-1): row = c>>5, x = (c&31)*16
    unsigned short* tm16 = (unsigned short*)&tmask[0][0];
    #pragma unroll
    for (int it = 0; it < (MROWS * 32 + 255) / 256; it++) {
        int c = it * 256 + threadIdx.x;
        if (c < MROWS * 32) {
            int row = c >> 5;
            int cx  = (c & 31) * 16;
            int gr  = r0 - 2 + row;
            unsigned int bits = 0;
            if ((unsigned)gr < (unsigned)Hdim) {
                const float* rp = tb + gr * Wdim + cx;
                float4 a = *(const float4*)(rp);
                float4 b = *(const float4*)(rp + 4);
                float4 d = *(const float4*)(rp + 8);
                float4 g = *(const float4*)(rp + 12);
                bits  = (a.x > .5f) ? 1u : 0u;      bits |= (a.y > .5f) ? 2u : 0u;
                bits |= (a.z > .5f) ? 4u : 0u;      bits |= (a.w > .5f) ? 8u : 0u;
                bits |= (b.x > .5f) ? 16u : 0u;     bits |= (b.y > .5f) ? 32u : 0u;
                bits |= (b.z > .5f) ? 64u : 0u;     bits |= (b.w > .5f) ? 128u : 0u;
                bits |= (d.x > .5f) ? 256u : 0u;    bits |= (d.y > .5f) ? 512u : 0u;
                bits |= (d.z > .5f) ? 1024u : 0u;   bits |= (d.w > .5f) ? 2048u : 0u;
                bits |= (g.x > .5f) ? 4096u : 0u;   bits |= (g.y > .5f) ? 8192u : 0u;
                bits |= (g.z > .5f) ? 16384u : 0u;  bits |= (g.w > .5f) ? 32768u : 0u;
            }
            tm16[c] = (unsigned short)bits;
        }
    }
    __syncthreads();

    // ---- Phase 2: boundary = dilate2 & ~erode2 (radius-2 L1 diamond), bitwise ----
    if (threadIdx.x < RSTRIP * WPR) {
        int row  = threadIdx.x >> 3;    // strip row 0..15
        int word = threadIdx.x & 7;
        int mr = row + 2;

        #define CW(r)  tmask[r][word]
        #define LW(r)  (word > 0 ? tmask[r][word - 1] : 0ULL)
        #define RW(r)  (word < WPR - 1 ? tmask[r][word + 1] : 0ULL)
        unsigned long long c0 = CW(mr),   l0 = LW(mr),   rr0 = RW(mr);
        unsigned long long cm = CW(mr-1), lm = LW(mr-1), rm  = RW(mr-1);
        unsigned long long cp = CW(mr+1), lp = LW(mr+1), rp  = RW(mr+1);
        unsigned long long cm2 = CW(mr-2);
        unsigned long long cp2 = CW(mr+2);
        #undef CW
        #undef LW
        #undef RW

        unsigned long long er =
            c0 & shl1(c0,l0) & shr1(c0,rr0) & shl2(c0,l0) & shr2(c0,rr0)
               & cm & shl1(cm,lm) & shr1(cm,rm)
               & cp & shl1(cp,lp) & shr1(cp,rp)
               & cm2 & cp2;
        unsigned long long di =
            c0 | shl1(c0,l0) | shr1(c0,rr0) | shl2(c0,l0) | shr2(c0,rr0)
               | cm | shl1(cm,lm) | shr1(cm,rm)
               | cp | shl1(cp,lp) | shr1(cp,rp)
               | cm2 | cp2;
        bmask[row][word] = di & ~er;
    }
    __syncthreads();

    // ---- Phase 3: elementwise math, float4 over the strip ----
    float s_focal = 0.f, s_inter = 0.f, s_p = 0.f, s_bw = 0.f;
    int s_tc = 0;
    #pragma unroll
    for (int it = 0; it < (RSTRIP * Wdim) / (256 * 4); it++) {
        int flat = it * 1024 + threadIdx.x * 4;   // px within strip
        int row  = flat >> 9;
        int x    = flat & (Wdim - 1);
        const float4 f4 = *(const float4*)(ib + (r0 + row) * Wdim + x);
        unsigned int tb4 = (unsigned int)((tmask[row + 2][x >> 6] >> (x & 63)) & 0xFULL);
        unsigned int bb4 = (unsigned int)((bmask[row][x >> 6]     >> (x & 63)) & 0xFULL);
        s_tc += __popc(tb4);
        const float xs[4] = {f4.x, f4.y, f4.z, f4.w};
        #pragma unroll
        for (int k = 0; k < 4; k++) {
            float xi = xs[k];
            bool tpos = (tb4 >> k) & 1;
            float e  = __expf(-fabsf(xi));                  // exp(-|x|)
            float bce = fmaxf(xi, 0.f) - (tpos ? xi : 0.f) + __logf(1.f + e);
            float rden = __builtin_amdgcn_rcpf(1.f + e);
            float p = (xi >= 0.f ? 1.f : e) * rden;         // sigmoid
            float pt = tpos ? p : 1.f - p;                  // == exp(-bce)
            float om = 1.f - pt;
            s_focal += 0.25f * om * om * bce;
            s_p     += p;
            s_inter += tpos ? p : 0.f;
            float wgt = ((bb4 >> k) & 1) ? 6.0f : 1.0f;     // 1 + THETA*boundary
            s_bw += bce * wgt;
        }
    }
    float s_t = (float)s_tc;

    // ---- Reduce: wave shuffle -> LDS -> block atomics ----
    #pragma unroll
    for (int off = 32; off > 0; off >>= 1) {
        s_focal += __shfl_down(s_focal, off);
        s_inter += __shfl_down(s_inter, off);
        s_p     += __shfl_down(s_p,     off);
        s_t     += __shfl_down(s_t,     off);
        s_bw    += __shfl_down(s_bw,    off);
    }
    if (lane == 0) {
        smem[wave][0] = s_focal; smem[wave][1] = s_inter; smem[wave][2] = s_p;
        smem[wave][3] = s_t;     smem[wave][4] = s_bw;
    }
    __syncthreads();
    if (threadIdx.x == 0) {
        double a0 = 0, a1 = 0, a2 = 0, a3 = 0, a4 = 0;
        #pragma unroll
        for (int w = 0; w < 4; w++) {
            a0 += smem[w][0]; a1 += smem[w][1]; a2 += smem[w][2];
            a3 += smem[w][3]; a4 += smem[w][4];
        }
        atomicAdd(&acc[0], a0);
        atomicAdd(&acc[1], a1);
        atomicAdd(&acc[2], a2);
        atomicAdd(&acc[3], a3);
        atomicAdd(&acc[4], a4);
        __threadfence();
        unsigned long long ticket = atomicAdd((unsigned long long*)&acc[5], 1ULL);
        if (ticket == (unsigned long long)(gridDim.x - 1)) {
            double b0 = atomicAdd(&acc[0], 0.0);
            double b1 = atomicAdd(&acc[1], 0.0);
            double b2 = atomicAdd(&acc[2], 0.0);
            double b3 = atomicAdd(&acc[3], 0.0);
            double b4 = atomicAdd(&acc[4], 0.0);
            double invN = 1.0 / (double)(64 * HW);
            double focal_loss = b0 * invN;
            double dice = (2.0 * b1 + 1e-6) / (b2 + b3 + 1e-6);
            double boundary_loss = b4 * invN;
            out[0] = (float)(0.3 * focal_loss + 0.4 * (1.0 - dice) + 0.3 * boundary_loss);
        }
    }
}

extern "C" void kernel_launch(void* const* d_in, const int* in_sizes, int n_in,
                              void* d_out, int out_size, void* d_ws, size_t ws_size,
                              hipStream_t stream) {
    const float* inp = (const float*)d_in[0];
    const float* tgt = (const float*)d_in[1];
    float* out = (float*)d_out;
    double* acc = (double*)d_ws;

    zero_ws_kernel<<<1, 64, 0, stream>>>(acc);
    combined_loss_kernel<<<NBLK, 256, 0, stream>>>(inp, tgt, acc, out);
}